// Round 3
// baseline (34488.562 us; speedup 1.0000x reference)
//
#include <hip/hip_runtime.h>

#define TT   1024
#define BB   64
#define DIN  256
#define HH   512
#define ROWS 8              // batch rows per block
#define KCW  48             // K elements per K-chunk (16 chunks * 48 = 768)
#define CHUNK_W 52          // padded chunk stride in LDS words (48 + 4 pad)
#define ROW_W (16 * CHUNK_W) // 832 words per staged row

// Persistent kernel, PLAIN launch: grid = 256 blocks (8 rowgrps x 32 colgrps),
// ~1 block/CU -> all co-resident on the 256-CU device. Each block owns
// 8 batch rows x 16 h-cols (= 64 z-cols across 4 gates). W slice lives in
// REGISTERS (192 VGPRs/thread) for all 1024 steps. h_{t-1} exchanged through
// d_out; rowgrp-local (32-block) monotonic barrier per step, device scope.
__global__ __launch_bounds__(256, 1)
void lstm_persist(const float* __restrict__ x_all,  // [1024][64][256]
                  const float* __restrict__ W4,     // [768][2048]
                  const float* __restrict__ b4,     // [2048]
                  float* out,                        // [1024][64][512] + hx + cx
                  const float* h0,                   // [64][512] zeros
                  unsigned int* bar)                 // 8 counters, 256B apart
{
    __shared__ float sH[ROWS * ROW_W];       // staged [x_t, h_{t-1}] rows, 26.6 KB
    __shared__ float sP[ROWS * 64 * 20];     // K-split partials, 40 KB
    __shared__ float sC[ROWS * 16];          // c state, block-local

    const int tid = threadIdx.x;
    const int bid = blockIdx.x;
    const int rg  = bid & 7;                 // rowgrp (XCD round-robin heuristic)
    const int cgb = bid >> 3;                // colgrp 0..31
    const int r0  = rg * ROWS;               // batch row base
    const int hc0 = cgb * 16;                // h-col base

    // compute-phase coords: 16 col-groups x 16 K-chunks
    const int cg = tid & 15;                 // owns 4 z-cols
    const int kc = tid >> 4;                 // K-chunk 0..15
    const int l0 = cg * 4;                   // local z-col base 0..60
    const int gate = l0 >> 4;
    const int zc0 = gate * 512 + hc0 + (l0 & 15);
    const int k0 = kc * KCW;

    // ---- one-time: load W slice into registers (4 cols x 48 K) ----
    float4 w0[12], w1[12], w2[12], w3[12];
    #pragma unroll
    for (int k4 = 0; k4 < 12; ++k4) {
        const float* base = W4 + (size_t)(k0 + 4 * k4) * 2048 + zc0;
        float4 t0 = *(const float4*)(base);
        float4 t1 = *(const float4*)(base + 2048);
        float4 t2 = *(const float4*)(base + 4096);
        float4 t3 = *(const float4*)(base + 6144);
        w0[k4] = make_float4(t0.x, t1.x, t2.x, t3.x);
        w1[k4] = make_float4(t0.y, t1.y, t2.y, t3.y);
        w2[k4] = make_float4(t0.z, t1.z, t2.z, t3.z);
        w3[k4] = make_float4(t0.w, t1.w, t2.w, t3.w);
    }

    // ---- one-time: c init + bias hoist (reduce-phase threads) ----
    float bias0 = 0.f, bias1 = 0.f, bias2 = 0.f, bias3 = 0.f;
    if (tid < 128) {
        sC[tid] = 0.f;
        int hc = tid & 15;
        bias0 = b4[0 * 512 + hc0 + hc];
        bias1 = b4[1 * 512 + hc0 + hc];
        bias2 = b4[2 * 512 + hc0 + hc];
        bias3 = b4[3 * 512 + hc0 + hc];
    }

    unsigned int bar_target = 0;
    unsigned int* cnt = bar + rg * 64;       // 256-B-spaced counter

    for (int t = 0; t < TT; ++t) {
        const float* hsrc = (t == 0) ? h0 : (out + (size_t)(t - 1) * (BB * HH));

        // ---- stage combined [8 rows x 768] into swizzled LDS ----
        #pragma unroll
        for (int s = 0; s < 6; ++s) {
            int i = tid + s * 256;           // 0..1535 float4s
            int r = i / 192;
            int j = i - r * 192;             // float4 idx within row
            float4 v;
            if (j < 64) v = *(const float4*)(x_all + ((size_t)t * BB + (r0 + r)) * DIN + 4 * j);
            else        v = *(const float4*)(hsrc + (size_t)(r0 + r) * HH + 4 * (j - 64));
            int kw  = 4 * j;
            int ch  = kw / KCW;
            int off = kw - ch * KCW;
            *(float4*)&sH[r * ROW_W + ch * CHUNK_W + off] = v;
        }
        __syncthreads();

        // ---- compute: per thread 8 rows x 4 cols over its 48-K chunk ----
        #pragma unroll
        for (int r = 0; r < ROWS; ++r) {
            const float* hp = &sH[r * ROW_W + kc * CHUNK_W];
            float ax = 0.f, ay = 0.f, az = 0.f, aw = 0.f;
            #pragma unroll
            for (int k4 = 0; k4 < 12; ++k4) {
                float4 h4 = *(const float4*)(hp + 4 * k4);
                ax = fmaf(h4.x, w0[k4].x, ax); ax = fmaf(h4.y, w0[k4].y, ax);
                ax = fmaf(h4.z, w0[k4].z, ax); ax = fmaf(h4.w, w0[k4].w, ax);
                ay = fmaf(h4.x, w1[k4].x, ay); ay = fmaf(h4.y, w1[k4].y, ay);
                ay = fmaf(h4.z, w1[k4].z, ay); ay = fmaf(h4.w, w1[k4].w, ay);
                az = fmaf(h4.x, w2[k4].x, az); az = fmaf(h4.y, w2[k4].y, az);
                az = fmaf(h4.z, w2[k4].z, az); az = fmaf(h4.w, w2[k4].w, az);
                aw = fmaf(h4.x, w3[k4].x, aw); aw = fmaf(h4.y, w3[k4].y, aw);
                aw = fmaf(h4.z, w3[k4].z, aw); aw = fmaf(h4.w, w3[k4].w, aw);
            }
            // swizzled slots: (kc + 5*cg + j) & 15 -> <=2-way bank aliasing.
            // Reduce sums ALL 16 slots, so the permutation is transparent.
            float* pp = &sP[(r * 64 + l0) * 20];
            pp[0 * 20 + ((kc + 5 * cg + 0) & 15)] = ax;
            pp[1 * 20 + ((kc + 5 * cg + 1) & 15)] = ay;
            pp[2 * 20 + ((kc + 5 * cg + 2) & 15)] = az;
            pp[3 * 20 + ((kc + 5 * cg + 3) & 15)] = aw;
        }
        __syncthreads();

        // ---- reduce 16 partials, gates, c/h update (128 threads) ----
        if (tid < 128) {
            int rr = tid >> 4;
            int hc = tid & 15;
            float z[4];
            #pragma unroll
            for (int g = 0; g < 4; ++g) {
                const float* pp = &sP[(rr * 64 + g * 16 + hc) * 20];
                float s = 0.f;
                #pragma unroll
                for (int q = 0; q < 4; ++q) {      // rr-rotated order: breaks
                    int off = 4 * ((rr + q) & 3);  // the stride-1280 bank collapse
                    float4 a = *(const float4*)(pp + off);
                    s += ((a.x + a.y) + (a.z + a.w));
                }
                z[g] = s;
            }
            z[0] += bias0; z[1] += bias1; z[2] += bias2; z[3] += bias3;
            float f  = 1.f / (1.f + expf(-z[0]));
            float ii = 1.f / (1.f + expf(-z[1]));
            float gg = tanhf(z[2]);
            float o  = 1.f / (1.f + expf(-z[3]));
            float cn = f * sC[rr * 16 + hc] + ii * gg;
            sC[rr * 16 + hc] = cn;
            float hn = o * tanhf(cn);
            out[((size_t)t * BB + (r0 + rr)) * HH + hc0 + hc] = hn;
            if (t == TT - 1) {
                out[(size_t)TT * BB * HH + (size_t)(r0 + rr) * HH + hc0 + hc] = hn;            // hx
                out[(size_t)TT * BB * HH + BB * HH + (size_t)(r0 + rr) * HH + hc0 + hc] = cn;  // cx
            }
        }
        __syncthreads();   // sP reads done; h stores drained (vmcnt(0) at barrier)

        // ---- rowgrp-local monotonic barrier (device scope) ----
        bar_target += 32;
        if (tid == 0) {
            __threadfence();  // make this block's h writes device-visible
            __hip_atomic_fetch_add(cnt, 1u, __ATOMIC_RELEASE, __HIP_MEMORY_SCOPE_AGENT);
            while (__hip_atomic_load(cnt, __ATOMIC_ACQUIRE, __HIP_MEMORY_SCOPE_AGENT) < bar_target) {
                __builtin_amdgcn_s_sleep(1);
            }
        }
        __syncthreads();
        __threadfence();      // invalidate stale cached h before next-step reads
    }
}

extern "C" void kernel_launch(void* const* d_in, const int* in_sizes, int n_in,
                              void* d_out, int out_size, void* d_ws, size_t ws_size,
                              hipStream_t stream) {
    const float* x_all = (const float*)d_in[0];
    const float* W4    = (const float*)d_in[1];
    const float* b4    = (const float*)d_in[2];
    float* out = (float*)d_out;

    unsigned int* bar = (unsigned int*)d_ws;                    // 8 x 64 uints = 2 KB
    float* h0 = (float*)((char*)d_ws + 2048);                   // 64x512 zeros = 128 KB

    // ws re-poisoned 0xAA before every timed call: zero barrier counters + h0
    hipMemsetAsync(d_ws, 0, 2048 + (size_t)BB * HH * sizeof(float), stream);

    lstm_persist<<<dim3(256), dim3(256), 0, stream>>>(x_all, W4, b4, out, h0, bar);
}

// Round 4
// 16739.601 us; speedup vs baseline: 2.0603x; 2.0603x over previous
//
#include <hip/hip_runtime.h>

#define TT   1024
#define BB   64
#define DIN  256
#define HH   512
#define ROWS 8               // batch rows per block
#define KCW  48              // K elements per K-chunk (16 chunks * 48 = 768)
#define CHUNK_W 52           // padded chunk stride in LDS words (48 + 4 pad)
#define ROW_W (16 * CHUNK_W) // 832 words per staged row

// Persistent kernel, plain launch: 256 blocks (8 rowgrps x 32 colgrps), 1/CU.
// Block owns 8 batch rows x 16 h-cols (64 z-cols across 4 gates). W slice in
// registers/AGPRs. h exchanged through d_out. Per-step rowgrp barrier:
// release-add (arrive) -> x_{t+1} prefetch overlaps propagation -> RELAXED
// scoped poll -> single acquire fence by tid0. No per-thread fences.
__global__ __launch_bounds__(256, 1)
void lstm_persist(const float* __restrict__ x_all,  // [1024][64][256]
                  const float* __restrict__ W4,     // [768][2048]
                  const float* __restrict__ b4,     // [2048]
                  float* out,                        // [1024][64][512] + hx + cx
                  const float* h0,                   // [64][512] zeros
                  unsigned int* bar)                 // 8 counters, 256B apart
{
    __shared__ float sH[ROWS * ROW_W];       // staged [x_t, h_{t-1}], 26.6 KB
    __shared__ float sP[ROWS * 64 * 20];     // K-split partials, 40 KB
    __shared__ float sC[ROWS * 16];          // c state, block-local

    const int tid = threadIdx.x;
    const int bid = blockIdx.x;
    const int rg  = bid & 7;                 // rowgrp
    const int cgb = bid >> 3;                // colgrp 0..31
    const int r0  = rg * ROWS;
    const int hc0 = cgb * 16;

    const int cg = tid & 15;                 // owns 4 z-cols
    const int kc = tid >> 4;                 // K-chunk 0..15
    const int l0 = cg * 4;
    const int gate = l0 >> 4;
    const int zc0 = gate * 512 + hc0 + (l0 & 15);
    const int k0 = kc * KCW;

    // ---- precomputed staging offsets (t-invariant) ----
    int xL[2], xG[2];                        // x: 512 float4s, 2/thread
    #pragma unroll
    for (int s = 0; s < 2; ++s) {
        int i = tid + s * 256;
        int r = i >> 6, j = i & 63;
        int kw = 4 * j, ch = kw / KCW, off = kw - ch * KCW;
        xL[s] = r * ROW_W + ch * CHUNK_W + off;
        xG[s] = (r0 + r) * DIN + kw;
    }
    int hL[4], hG[4];                        // h: 1024 float4s, 4/thread
    #pragma unroll
    for (int s = 0; s < 4; ++s) {
        int i = tid + s * 256;
        int r = i >> 7, jj = i & 127;
        int kw = 256 + 4 * jj, ch = kw / KCW, off = kw - ch * KCW;
        hL[s] = r * ROW_W + ch * CHUNK_W + off;
        hG[s] = (r0 + r) * HH + 4 * jj;
    }

    // ---- one-time: W slice into registers (4 cols x 48 K) ----
    float4 w0[12], w1[12], w2[12], w3[12];
    #pragma unroll
    for (int k4 = 0; k4 < 12; ++k4) {
        const float* base = W4 + (size_t)(k0 + 4 * k4) * 2048 + zc0;
        float4 t0 = *(const float4*)(base);
        float4 t1 = *(const float4*)(base + 2048);
        float4 t2 = *(const float4*)(base + 4096);
        float4 t3 = *(const float4*)(base + 6144);
        w0[k4] = make_float4(t0.x, t1.x, t2.x, t3.x);
        w1[k4] = make_float4(t0.y, t1.y, t2.y, t3.y);
        w2[k4] = make_float4(t0.z, t1.z, t2.z, t3.z);
        w3[k4] = make_float4(t0.w, t1.w, t2.w, t3.w);
    }

    float bias0 = 0.f, bias1 = 0.f, bias2 = 0.f, bias3 = 0.f;
    if (tid < 128) {
        sC[tid] = 0.f;
        int hc = tid & 15;
        bias0 = b4[0 * 512 + hc0 + hc];
        bias1 = b4[1 * 512 + hc0 + hc];
        bias2 = b4[2 * 512 + hc0 + hc];
        bias3 = b4[3 * 512 + hc0 + hc];
    }

    unsigned int bar_target = 0;
    unsigned int* cnt = bar + rg * 64;

    // ---- pre-stage x for t=0 ----
    {
        const float* xb = x_all;             // t = 0
        #pragma unroll
        for (int s = 0; s < 2; ++s)
            *(float4*)&sH[xL[s]] = *(const float4*)(xb + xG[s]);
    }

    for (int t = 0; t < TT; ++t) {
        // ---- wait for h_{t-1} (t>0): relaxed poll + single acquire fence ----
        if (t > 0) {
            if (tid == 0) {
                while (__hip_atomic_load(cnt, __ATOMIC_RELAXED,
                                         __HIP_MEMORY_SCOPE_AGENT) < bar_target) { }
                __threadfence();             // one L1/L2 invalidate per step
            }
            __syncthreads();
        }

        // ---- stage h_{t-1} rows into LDS ----
        const float* hsrc = (t == 0) ? h0 : (out + (size_t)(t - 1) * (BB * HH));
        #pragma unroll
        for (int s = 0; s < 4; ++s)
            *(float4*)&sH[hL[s]] = *(const float4*)(hsrc + hG[s]);
        __syncthreads();

        // ---- compute: 8 rows x 4 cols over this thread's 48-K chunk ----
        #pragma unroll
        for (int r = 0; r < ROWS; ++r) {
            const float* hp = &sH[r * ROW_W + kc * CHUNK_W];
            float ax = 0.f, ay = 0.f, az = 0.f, aw = 0.f;
            #pragma unroll
            for (int k4 = 0; k4 < 12; ++k4) {
                float4 h4 = *(const float4*)(hp + 4 * k4);
                ax = fmaf(h4.x, w0[k4].x, ax); ax = fmaf(h4.y, w0[k4].y, ax);
                ax = fmaf(h4.z, w0[k4].z, ax); ax = fmaf(h4.w, w0[k4].w, ax);
                ay = fmaf(h4.x, w1[k4].x, ay); ay = fmaf(h4.y, w1[k4].y, ay);
                ay = fmaf(h4.z, w1[k4].z, ay); ay = fmaf(h4.w, w1[k4].w, ay);
                az = fmaf(h4.x, w2[k4].x, az); az = fmaf(h4.y, w2[k4].y, az);
                az = fmaf(h4.z, w2[k4].z, az); az = fmaf(h4.w, w2[k4].w, az);
                aw = fmaf(h4.x, w3[k4].x, aw); aw = fmaf(h4.y, w3[k4].y, aw);
                aw = fmaf(h4.z, w3[k4].z, aw); aw = fmaf(h4.w, w3[k4].w, aw);
            }
            float* pp = &sP[(r * 64 + l0) * 20];
            pp[0 * 20 + ((kc + 5 * cg + 0) & 15)] = ax;
            pp[1 * 20 + ((kc + 5 * cg + 1) & 15)] = ay;
            pp[2 * 20 + ((kc + 5 * cg + 2) & 15)] = az;
            pp[3 * 20 + ((kc + 5 * cg + 3) & 15)] = aw;
        }
        __syncthreads();

        // ---- reduce partials, gates, c/h update (128 threads) ----
        if (tid < 128) {
            int rr = tid >> 4;
            int hc = tid & 15;
            float z[4];
            #pragma unroll
            for (int g = 0; g < 4; ++g) {
                const float* pp = &sP[(rr * 64 + g * 16 + hc) * 20];
                float s = 0.f;
                #pragma unroll
                for (int q = 0; q < 4; ++q) {
                    int off = 4 * ((rr + q) & 3);
                    float4 a = *(const float4*)(pp + off);
                    s += ((a.x + a.y) + (a.z + a.w));
                }
                z[g] = s;
            }
            z[0] += bias0; z[1] += bias1; z[2] += bias2; z[3] += bias3;
            float f  = 1.f / (1.f + expf(-z[0]));
            float ii = 1.f / (1.f + expf(-z[1]));
            float gg = tanhf(z[2]);
            float o  = 1.f / (1.f + expf(-z[3]));
            float cn = f * sC[rr * 16 + hc] + ii * gg;
            sC[rr * 16 + hc] = cn;
            float hn = o * tanhf(cn);
            out[((size_t)t * BB + (r0 + rr)) * HH + hc0 + hc] = hn;
            if (t == TT - 1) {
                out[(size_t)TT * BB * HH + (size_t)(r0 + rr) * HH + hc0 + hc] = hn;            // hx
                out[(size_t)TT * BB * HH + BB * HH + (size_t)(r0 + rr) * HH + hc0 + hc] = cn;  // cx
            }
        }
        __syncthreads();   // drains h stores to L2 (vmcnt(0) before s_barrier)

        // ---- arrive (release), then hide propagation behind x prefetch ----
        bar_target += 32;
        if (tid == 0)
            __hip_atomic_fetch_add(cnt, 1u, __ATOMIC_RELEASE, __HIP_MEMORY_SCOPE_AGENT);
        if (t + 1 < TT) {
            const float* xb = x_all + (size_t)(t + 1) * BB * DIN;
            #pragma unroll
            for (int s = 0; s < 2; ++s)
                *(float4*)&sH[xL[s]] = *(const float4*)(xb + xG[s]);
        }
    }
}

extern "C" void kernel_launch(void* const* d_in, const int* in_sizes, int n_in,
                              void* d_out, int out_size, void* d_ws, size_t ws_size,
                              hipStream_t stream) {
    const float* x_all = (const float*)d_in[0];
    const float* W4    = (const float*)d_in[1];
    const float* b4    = (const float*)d_in[2];
    float* out = (float*)d_out;

    unsigned int* bar = (unsigned int*)d_ws;                    // 8 x 64 uints
    float* h0 = (float*)((char*)d_ws + 2048);                   // 64x512 zeros

    hipMemsetAsync(d_ws, 0, 2048 + (size_t)BB * HH * sizeof(float), stream);

    lstm_persist<<<dim3(256), dim3(256), 0, stream>>>(x_all, W4, b4, out, h0, bar);
}